// Round 2
// baseline (239.756 us; speedup 1.0000x reference)
//
#include <hip/hip_runtime.h>

// JointBilateralFilter: B=16,C=1,H=768,W=1024 fp32, 9x9, sigma_s=2, sigma_r=0.1.
// Facts: valid = (sparse != 1.0); constant pad 1.0 => out-of-image taps never
// contribute (reflect-pad of depth is dead code). ~5% valid density.
// R2 structure: NO LDS list. Per 8x8 tile (one wave), scan the 16x16 halo in
// 4 chunks of 64; ballot the valid lanes, then a SCALAR bit-scan loop
// (s_ff1 + v_readlane) broadcasts each valid point's (sparse,depth) from the
// staging registers. Entry coordinates derive from the bit index in SALU.
// Removes: LDS build/read (~120cyc serial lgkm stalls), __syncthreads,
// 64-bit compaction math. Inner pair cost ~18 wave64 VALU ops.

#define HH 768
#define WW 1024
#define BB 16

#define COEF_S (-0.18033688011112042f)   /* -log2(e)/8   */
#define COEF_R (-72.13475204444817f)     /* -50*log2(e)  */

__global__ __launch_bounds__(256) void jbf_kernel(
    const float* __restrict__ sparse,
    const float* __restrict__ depth,
    float* __restrict__ out)
{
    const int tid  = (int)threadIdx.x;
    const int lane = tid & 63;
    const int wv   = tid >> 6;                     // 4 independent waves / block
    // block covers 16x16; wave wv covers the 8x8 sub-tile (wv>>1, wv&1)
    const int tx = ((int)blockIdx.x << 4) + ((wv & 1) << 3);
    const int ty = ((int)blockIdx.y << 4) + ((wv >> 1) << 3);
    const size_t plane = (size_t)blockIdx.z * (size_t)(HH * WW);
    const float* sp = sparse + plane;
    const float* dp = depth  + plane;

    const int my = lane >> 3, mx = lane & 7;       // position in 8x8 tile
    const int gy = ty + my,  gx = tx + mx;
    const float myd = dp[gy * WW + gx];
    const int myp = my + 4;                        // dyi = ry - myp
    const int mxp = mx + 4;

    // halo-region lane coords (x part is chunk-invariant; only y varies)
    const int rx = lane & 15;                      // 0..15
    const int ry0 = lane >> 4;                     // 0..3, +4 per chunk
    const int px  = tx - 4 + rx;
    const int pxc = min(max(px, 0), WW - 1);       // v_med3
    const bool inx = (unsigned)px < (unsigned)WW;  // one cmp

    float num = 0.0f, den = 0.0f;

    #pragma unroll
    for (int chunk = 0; chunk < 4; ++chunk) {
        const int ry = (chunk << 2) + ry0;         // 0..15
        const int py = ty - 4 + ry;
        const int pyc = min(max(py, 0), HH - 1);   // v_med3
        const bool iny = (unsigned)py < (unsigned)HH;
        const int off = pyc * WW + pxc;            // v_lshl_add

        const float sv = sp[off];                  // clamped => always safe
        const bool valid = inx & iny & (sv != 1.0f);
        float dv = 0.0f;
        if (valid) dv = dp[off];                   // rare lanes, masked load

        unsigned long long m = __ballot(valid);
        while (m) {                                // scalar-controlled loop
            const int b = (int)__builtin_ctzll(m); // s_ff1_i32_b64 -> SGPR
            m &= (m - 1ull);
            const float sv_b = __int_as_float(
                __builtin_amdgcn_readlane(__float_as_int(sv), b));
            const float dv_b = __int_as_float(
                __builtin_amdgcn_readlane(__float_as_int(dv), b));
            const int bry = (chunk << 2) + (b >> 4);   // SALU
            const int brx = b & 15;                    // SALU
            const int dyi = bry - myp;                 // per-lane VALU from here
            const int dxi = brx - mxp;
            const int dy2 = dyi * dyi;                 // i24 muls
            const int dx2 = dxi * dxi;
            const int r2i = dy2 + dx2;
            const bool inbox = (unsigned)max(dy2, dx2) <= 16u;  // 9x9 box
            const float r2f = (float)r2i;
            const float diff = dv_b - myd;
            const float arg = fmaf(diff * diff, COEF_R, r2f * COEF_S);
            float w = __builtin_amdgcn_exp2f(arg);
            w = inbox ? w : 0.0f;
            num = fmaf(w, sv_b, num);
            den += w;
        }
    }

    float res = num * __builtin_amdgcn_rcpf(den + 1e-8f);
    res = (den < 1e-8f) ? 1.0f : res;
    out[plane + (size_t)(gy * WW + gx)] = res;
}

extern "C" void kernel_launch(void* const* d_in, const int* in_sizes, int n_in,
                              void* d_out, int out_size, void* d_ws, size_t ws_size,
                              hipStream_t stream)
{
    const float* sparse = (const float*)d_in[0];
    const float* depth  = (const float*)d_in[1];
    float* out = (float*)d_out;
    dim3 grid(WW / 16, HH / 16, BB);   // 64 x 48 x 16 blocks, 4 waves each
    jbf_kernel<<<grid, dim3(256, 1, 1), 0, stream>>>(sparse, depth, out);
}

// Round 3
// 210.978 us; speedup vs baseline: 1.1364x; 1.1364x over previous
//
#include <hip/hip_runtime.h>

// JointBilateralFilter: B=16,C=1,H=768,W=1024 fp32, 9x9, sigma_s=2, sigma_r=0.1.
// valid = (sparse != 1.0); constant pad 1.0 => out-of-image taps never contribute
// (reflect-pad of depth is dead code). ~5% valid density.
//
// R3 structure: per 8x8 tile (one wave), stage the clamped 16x16 window with ONE
// float4 load per lane for sparse and ONE for depth (no per-cell clamps, no
// predicated loads, no sv->dv dependency). Window origin is clamped in SALU;
// the 9x9 box test inside the loop kills out-of-halo cells at image edges.
// Then 4 ballot rounds (one per float4 component) + scalar bit-scan broadcast.

#define HH 768
#define WW 1024
#define BB 16

#define COEF_S (-0.18033688011112042f)   /* -log2(e)/8   */
#define COEF_R (-72.13475204444817f)     /* -50*log2(e)  */

__global__ __launch_bounds__(256) void jbf_kernel(
    const float* __restrict__ sparse,
    const float* __restrict__ depth,
    float* __restrict__ out)
{
    const int tid  = (int)threadIdx.x;
    const int lane = tid & 63;
    const int wv   = tid >> 6;                     // 4 independent waves / block
    const int tx = ((int)blockIdx.x << 4) + ((wv & 1) << 3);
    const int ty = ((int)blockIdx.y << 4) + ((wv >> 1) << 3);
    const size_t plane = (size_t)blockIdx.z * (size_t)(HH * WW);
    const float* sp = sparse + plane;
    const float* dp = depth  + plane;

    // clamped 16x16 staging window; box test later rejects out-of-halo cells
    const int px0 = min(max(tx - 4, 0), WW - 16);  // SALU, wave-uniform
    const int py0 = min(max(ty - 4, 0), HH - 16);

    const int ry  = lane >> 2;                     // 0..15 window row
    const int rxg = (lane & 3) << 2;               // 0,4,8,12 float4 group
    const int woff = (py0 + ry) * WW + (px0 + rxg);

    const float4 s4 = *(const float4*)(sp + woff); // 16B aligned (px0%4==0)
    const float4 d4 = *(const float4*)(dp + woff);

    const int my = lane >> 3, mx = lane & 7;
    const int gy = ty + my,  gx = tx + mx;
    const float myd = dp[gy * WW + gx];

    float num = 0.0f, den = 0.0f;

    const float sva[4] = {s4.x, s4.y, s4.z, s4.w};
    const float dva[4] = {d4.x, d4.y, d4.z, d4.w};

    #pragma unroll
    for (int k = 0; k < 4; ++k) {                  // component k: cell x = px0+k+4*(b&3)
        const float svk = sva[k];
        const float dvk = dva[k];
        unsigned long long m = __ballot(svk != 1.0f);
        while (m) {                                // scalar-controlled, wave-uniform
            const int b = (int)__builtin_ctzll(m); // s_ff1
            m &= (m - 1ull);
            const float sv_b = __int_as_float(
                __builtin_amdgcn_readlane(__float_as_int(svk), b));
            const float dv_b = __int_as_float(
                __builtin_amdgcn_readlane(__float_as_int(dvk), b));
            const int ey = py0 + (b >> 2);              // SALU
            const int ex = px0 + k + ((b & 3) << 2);    // SALU
            const int dyi = ey - gy;                    // VALU from here
            const int dxi = ex - gx;
            const int dy2 = dyi * dyi;                  // i24 muls
            const int dx2 = dxi * dxi;
            const bool inbox = (unsigned)max(dy2, dx2) <= 16u;
            const float r2f = (float)(dy2 + dx2);
            const float diff = dv_b - myd;
            const float arg = fmaf(diff * diff, COEF_R, r2f * COEF_S);
            float w = __builtin_amdgcn_exp2f(arg);
            w = inbox ? w : 0.0f;
            num = fmaf(w, sv_b, num);
            den += w;
        }
    }

    float res = num * __builtin_amdgcn_rcpf(den + 1e-8f);
    res = (den < 1e-8f) ? 1.0f : res;
    out[plane + (size_t)(gy * WW + gx)] = res;
}

extern "C" void kernel_launch(void* const* d_in, const int* in_sizes, int n_in,
                              void* d_out, int out_size, void* d_ws, size_t ws_size,
                              hipStream_t stream)
{
    const float* sparse = (const float*)d_in[0];
    const float* depth  = (const float*)d_in[1];
    float* out = (float*)d_out;
    dim3 grid(WW / 16, HH / 16, BB);   // 64 x 48 x 16 blocks, 4 waves each
    jbf_kernel<<<grid, dim3(256, 1, 1), 0, stream>>>(sparse, depth, out);
}

// Round 4
// 194.165 us; speedup vs baseline: 1.2348x; 1.0866x over previous
//
#include <hip/hip_runtime.h>

// JointBilateralFilter: B=16,C=1,H=768,W=1024 fp32, 9x9, sigma_s=2, sigma_r=0.1.
// valid = (sparse != 1.0); constant pad 1.0 => out-of-image taps never contribute
// (reflect-pad of depth is dead code). ~5% valid density.
//
// R4: R3 structure (one float4 sparse + one float4 depth load per lane stages a
// clamped 16x16 window; 4 ballot rounds + scalar bit-scan broadcast) PLUS:
//  * readfirstlane-uniformized tile constants (tx,ty,px0,py0) so the per-entry
//    coordinate math is true SALU (they were divergent-by-construction via
//    wv=threadIdx.x>>6, forcing the whole entry body onto the VALU pipe).
//  * float weight pipeline with abs-modifier box test (max(|dy|,|dx|)<4.5).
//  * bit-scan unrolled 2 entries/trip into independent A/B accumulator chains
//    (halves serial exp-chain latency exposure).

#define HH 768
#define WW 1024
#define BB 16

#define COEF_S (-0.18033688011112042f)   /* -log2(e)/8   */
#define COEF_R (-72.13475204444817f)     /* -50*log2(e)  */

__device__ __forceinline__ int rfl(int x) {
    return __builtin_amdgcn_readfirstlane(x);
}
__device__ __forceinline__ float rlanef(float v, int b) {
    return __int_as_float(__builtin_amdgcn_readlane(__float_as_int(v), b));
}

__device__ __forceinline__ void entry_body(
    int b, int k, float svk, float dvk,
    int px0, int py0, float fgy, float fgx, float myd,
    float& num, float& den)
{
    const float sv_b = rlanef(svk, b);
    const float dv_b = rlanef(dvk, b);
    const float eyf = (float)(py0 + (b >> 2));           // SALU int, v_cvt s->v
    const float exf = (float)(px0 + k + ((b & 3) << 2)); // SALU int, v_cvt s->v
    const float dy = eyf - fgy;
    const float dx = exf - fgx;
    const float r2 = fmaf(dy, dy, dx * dx);
    const bool inbox = fmaxf(fabsf(dy), fabsf(dx)) < 4.5f; // abs mods are free
    const float diff = dv_b - myd;
    const float arg = fmaf(diff, diff * COEF_R, r2 * COEF_S);
    float w = __builtin_amdgcn_exp2f(arg);
    w = inbox ? w : 0.0f;
    num = fmaf(w, sv_b, num);
    den += w;
}

__global__ __launch_bounds__(256) void jbf_kernel(
    const float* __restrict__ sparse,
    const float* __restrict__ depth,
    float* __restrict__ out)
{
    const int tid  = (int)threadIdx.x;
    const int lane = tid & 63;
    const int wv   = tid >> 6;                     // 4 independent waves / block
    // wave-uniform tile constants -> force into SGPRs
    const int tx = rfl(((int)blockIdx.x << 4) + ((wv & 1) << 3));
    const int ty = rfl(((int)blockIdx.y << 4) + ((wv >> 1) << 3));
    const int px0 = rfl(min(max(tx - 4, 0), WW - 16));
    const int py0 = rfl(min(max(ty - 4, 0), HH - 16));

    const size_t plane = (size_t)blockIdx.z * (size_t)(HH * WW);
    const float* sp = sparse + plane;
    const float* dp = depth  + plane;

    // stage clamped 16x16 window: one float4 per lane per input
    const int ry  = lane >> 2;                     // 0..15 window row
    const int rxg = (lane & 3) << 2;               // 0,4,8,12 float4 group
    const int woff = (py0 + ry) * WW + (px0 + rxg);
    const float4 s4 = *(const float4*)(sp + woff); // px0 % 4 == 0 => aligned
    const float4 d4 = *(const float4*)(dp + woff);

    const int my = lane >> 3, mx = lane & 7;
    const int gy = ty + my,  gx = tx + mx;
    const float myd = dp[gy * WW + gx];
    const float fgy = (float)gy, fgx = (float)gx;

    float numA = 0.0f, denA = 0.0f, numB = 0.0f, denB = 0.0f;

    #pragma unroll
    for (int k = 0; k < 4; ++k) {
        const float svk = (k == 0) ? s4.x : (k == 1) ? s4.y : (k == 2) ? s4.z : s4.w;
        const float dvk = (k == 0) ? d4.x : (k == 1) ? d4.y : (k == 2) ? d4.z : d4.w;
        unsigned long long m = __ballot(svk != 1.0f);
        while (m) {                                // uniform control flow
            const int b0 = (int)__builtin_ctzll(m);
            m &= (m - 1ull);
            entry_body(b0, k, svk, dvk, px0, py0, fgy, fgx, myd, numA, denA);
            if (m) {                               // second, independent chain
                const int b1 = (int)__builtin_ctzll(m);
                m &= (m - 1ull);
                entry_body(b1, k, svk, dvk, px0, py0, fgy, fgx, myd, numB, denB);
            }
        }
    }

    const float num = numA + numB;
    const float den = denA + denB;
    float res = num * __builtin_amdgcn_rcpf(den + 1e-8f);
    res = (den < 1e-8f) ? 1.0f : res;
    out[plane + (size_t)(gy * WW + gx)] = res;
}

extern "C" void kernel_launch(void* const* d_in, const int* in_sizes, int n_in,
                              void* d_out, int out_size, void* d_ws, size_t ws_size,
                              hipStream_t stream)
{
    const float* sparse = (const float*)d_in[0];
    const float* depth  = (const float*)d_in[1];
    float* out = (float*)d_out;
    dim3 grid(WW / 16, HH / 16, BB);   // 64 x 48 x 16 blocks, 4 waves each
    jbf_kernel<<<grid, dim3(256, 1, 1), 0, stream>>>(sparse, depth, out);
}